// Round 9
// baseline (371.379 us; speedup 1.0000x reference)
//
#include <hip/hip_runtime.h>
#include <math.h>

#define NNODES 10000
#define MPAD   10240               // 80*128, padded row count for MFMA GEMM
#define NEDGES 160000
#define ETOT   (NEDGES + NNODES)   // 170000, with self loops
#define NGRAPH 64
#define LN_EPS 1e-5f
#define NEG_SLOPE 0.2f

typedef _Float16 f16x8 __attribute__((ext_vector_type(8)));
typedef _Float16 f16x4 __attribute__((ext_vector_type(4)));
typedef _Float16 f16x2 __attribute__((ext_vector_type(2)));
typedef float    f32x4 __attribute__((ext_vector_type(4)));

__device__ __forceinline__ f16x4 pk_abs4(f16x4 v) {
    uint2 u; __builtin_memcpy(&u, &v, 8);
    u.x &= 0x7fff7fffu; u.y &= 0x7fff7fffu;
    f16x4 r; __builtin_memcpy(&r, &u, 8);
    return r;
}
__device__ __forceinline__ f16x2 pk_abs2(f16x2 v) {
    unsigned u; __builtin_memcpy(&u, &v, 4);
    u &= 0x7fff7fffu;
    f16x2 r; __builtin_memcpy(&r, &u, 4);
    return r;
}

// ---------- convert x [10000][771] fp32 -> A [MPAD][800] fp16 (zero pad) ----------
__global__ __launch_bounds__(256) void convert_x(
    const float* __restrict__ x, _Float16* __restrict__ ah)
{
    int idx = blockIdx.x * blockDim.x + threadIdx.x;
    if (idx >= MPAD * 800) return;
    int r = idx / 800, k = idx - r * 800;
    float v = (r < NNODES && k < 771) ? x[(size_t)r * 771 + k] : 0.f;
    ah[idx] = (_Float16)v;
}

// ---------- pack weights: Wl|Wr [K][NW] -> B [Np][Kp] fp16 transposed ----------
__global__ __launch_bounds__(256) void pack_w(
    const float* __restrict__ Wl, const float* __restrict__ Wr,
    const float* __restrict__ bl, const float* __restrict__ br,
    _Float16* __restrict__ bh, float* __restrict__ biasp,
    int K, int Kp, int NW, int Np)
{
    int idx = blockIdx.x * blockDim.x + threadIdx.x;
    if (idx < Np) biasp[idx] = (idx < NW) ? bl[idx] : br[idx - NW];
    if (idx >= Np * Kp) return;
    int n = idx / Kp, k = idx - n * Kp;
    float v = 0.f;
    if (k < K) v = (n < NW) ? Wl[(size_t)k * NW + n] : Wr[(size_t)k * NW + (n - NW)];
    bh[idx] = (_Float16)v;
}

// ---------- fp16 MFMA GEMM: C[M][N] = A[M][Kp] @ B[Kp][N] + bias ----------
// 128x128 tile, 4 waves x 64x64, BK=32, 16x16x32 f16 MFMA, XCD-aware 1-D grid,
// 2-way-aliasing LDS swizzle. Epilogue: cols<N/2 -> xl fp16; cols>=N/2 -> xr fp16.
__global__ __launch_bounds__(256) void gemm_mfma(
    const _Float16* __restrict__ Ah, const _Float16* __restrict__ Bh,
    const float* __restrict__ bias,
    _Float16* __restrict__ xlh, _Float16* __restrict__ xrh,
    int M, int Kp, int N, int lognbx)
{
    __shared__ __align__(16) _Float16 sAh[128 * 32];
    __shared__ __align__(16) _Float16 sBh[128 * 32];

    const int tid  = threadIdx.x;
    const int lane = tid & 63;
    const int wave = tid >> 6;
    const int L    = blockIdx.x;
    const int xcd  = L & 7;
    const int t    = L >> 3;
    const int bx   = t & ((1 << lognbx) - 1);
    const int by   = xcd + 8 * (t >> lognbx);
    const int row0 = by * 128;
    const int col0 = bx * 128;
    const int wr = (wave >> 1) * 64;
    const int wc = (wave & 1) * 64;
    const int fm = lane & 15;
    const int fq = lane >> 4;

    f32x4 acc[4][4] = {};

    for (int k0 = 0; k0 < Kp; k0 += 32) {
#pragma unroll
        for (int it = 0; it < 2; ++it) {
            int c  = tid + it * 256;             // 0..511 16B chunks per tile
            int r  = c >> 2;
            int kc = (c & 3) ^ ((r >> 1) & 3);   // swizzled global k-chunk
            size_t ga = (size_t)(row0 + r) * Kp + k0 + kc * 8;
            size_t gb = (size_t)(col0 + r) * Kp + k0 + kc * 8;
            __builtin_amdgcn_global_load_lds(
                (const __attribute__((address_space(1))) void*)(Ah + ga),
                (__attribute__((address_space(3))) void*)(sAh + c * 8), 16, 0, 0);
            __builtin_amdgcn_global_load_lds(
                (const __attribute__((address_space(1))) void*)(Bh + gb),
                (__attribute__((address_space(3))) void*)(sBh + c * 8), 16, 0, 0);
        }
        __syncthreads();

        f16x8 fah[4], fbh[4];
#pragma unroll
        for (int mi = 0; mi < 4; ++mi) {
            int m = wr + mi * 16 + fm;
            int off = (m * 4 + (fq ^ ((m >> 1) & 3))) * 8;
            fah[mi] = *(const f16x8*)(sAh + off);
        }
#pragma unroll
        for (int ni = 0; ni < 4; ++ni) {
            int n = wc + ni * 16 + fm;
            int off = (n * 4 + (fq ^ ((n >> 1) & 3))) * 8;
            fbh[ni] = *(const f16x8*)(sBh + off);
        }
#pragma unroll
        for (int mi = 0; mi < 4; ++mi)
#pragma unroll
            for (int ni = 0; ni < 4; ++ni)
                acc[mi][ni] = __builtin_amdgcn_mfma_f32_16x16x32_f16(fah[mi], fbh[ni], acc[mi][ni], 0, 0, 0);
        __syncthreads();
    }

    const int NH = N >> 1;
    float bv[4];
#pragma unroll
    for (int ni = 0; ni < 4; ++ni) bv[ni] = bias[col0 + wc + ni * 16 + fm];
#pragma unroll
    for (int mi = 0; mi < 4; ++mi) {
        int grb = row0 + wr + mi * 16 + fq * 4;
#pragma unroll
        for (int reg = 0; reg < 4; ++reg) {
            int gr = grb + reg;
            if (gr < M) {
#pragma unroll
                for (int ni = 0; ni < 4; ++ni) {
                    int gc = col0 + wc + ni * 16 + fm;
                    float val = acc[mi][ni][reg] + bv[ni];
                    if (gc < NH) xlh[(size_t)gr * NH + gc] = (_Float16)val;
                    else         xrh[(size_t)gr * NH + gc - NH] = (_Float16)val;
                }
            }
        }
    }
}

// ---------- CSR build ----------
__global__ __launch_bounds__(256) void hist_kernel(
    const int* __restrict__ ei, int* __restrict__ deg)
{
    int e = blockIdx.x * blockDim.x + threadIdx.x;
    if (e >= ETOT) return;
    int d = (e < NEDGES) ? ei[NEDGES + e] : e - NEDGES;
    atomicAdd(&deg[d], 1);
}

__global__ __launch_bounds__(256) void scan_kernel(
    const int* __restrict__ deg, int* __restrict__ rowptr)
{
    __shared__ int partial[256];
    const int t = threadIdx.x;
    const int CH = (NNODES + 255) / 256;
    const int lo = t * CH, hi = min(lo + CH, NNODES);
    int s = 0;
    for (int i = lo; i < hi; i++) s += deg[i];
    partial[t] = s;
    __syncthreads();
    for (int off = 1; off < 256; off <<= 1) {
        int v = (t >= off) ? partial[t - off] : 0;
        __syncthreads();
        partial[t] += v;
        __syncthreads();
    }
    int run = partial[t] - s;
    for (int i = lo; i < hi; i++) { rowptr[i] = run; run += deg[i]; }
    if (t == 255) rowptr[NNODES] = partial[255];
}

__global__ __launch_bounds__(256) void scatter_kernel(
    const int* __restrict__ ei, const int* __restrict__ rowptr,
    int* __restrict__ cursor, int* __restrict__ perm_src)
{
    int e = blockIdx.x * blockDim.x + threadIdx.x;
    if (e >= ETOT) return;
    int s, d;
    if (e < NEDGES) { s = ei[e]; d = ei[NEDGES + e]; }
    else { s = e - NEDGES; d = s; }
    int pos = atomicAdd(&cursor[d], 1);
    perm_src[rowptr[d] + pos] = s;
}

// ---------- fused GATv2 edge phase + bias + LayerNorm + ELU, HC=512, H=4 ----------
// TWO waves per node (4 ch/lane): each wave owns 2 complete heads (head group =
// 32 lanes), so softmax is wave-local. LN stats combined across the wave pair
// via LDS. Edge loop: depth-4 load pipeline, clamped branch-free prefetch.
// Always emits fp16 (next layer's GEMM A); pad rows zeroed (NNODES even ->
// blocks are uniformly real or pad, no barrier divergence).
__global__ __launch_bounds__(256) void gat_ln512(
    const _Float16* __restrict__ xlh, const _Float16* __restrict__ xrh,
    const float* __restrict__ att, const float* __restrict__ bo,
    const float* __restrict__ gam, const float* __restrict__ bet,
    const int* __restrict__ rowptr, const int* __restrict__ perm_src,
    _Float16* __restrict__ ah)
{
    const int lane = threadIdx.x & 63;
    const int wv   = threadIdx.x >> 6;            // 0..3
    const int node = blockIdx.x * 2 + (wv >> 1);  // 2 nodes per block
    const int half = wv & 1;
    const int base = half * 256 + lane * 4;       // this wave's 256-ch half

    if (node >= NNODES) {                         // whole block is pad rows
        if (node < MPAD) {
            f16x4 z = {};
            *(f16x4*)(ah + (size_t)node * 512 + base) = z;
        }
        return;
    }

    const f16x4 xrp = *(const f16x4*)(xrh + (size_t)node * 512 + base);
    f16x4 w06, w04;
    {
        float4 w0 = *(const float4*)(att + base);
        float wa[4] = { w0.x, w0.y, w0.z, w0.w };
#pragma unroll
        for (int j = 0; j < 4; j++) {
            w06[j] = (_Float16)(0.6f * wa[j]);
            w04[j] = (_Float16)(0.4f * wa[j]);
        }
    }

    float l = 0.f;
    float acc[4] = {};

    auto edge_upd = [&](const f16x4 c0) {
        f16x4 v = c0 + xrp;
        f16x4 s = w06 * v + w04 * pk_abs4(v);
        float part = (float)s[0] + (float)s[1] + (float)s[2] + (float)s[3];
#pragma unroll
        for (int off = 16; off > 0; off >>= 1) part += __shfl_xor(part, off);
        float pe = __expf(part);
        l += pe;
#pragma unroll
        for (int j = 0; j < 4; j++) acc[j] += pe * (float)c0[j];
    };

    const int r0 = rowptr[node], r1 = rowptr[node + 1];
    {
        int sN[4];
        f16x4 rr[4];
#pragma unroll
        for (int i = 0; i < 4; i++) {
            int si = perm_src[min(r0 + i, r1 - 1)];
            rr[i] = *(const f16x4*)(xlh + (size_t)si * 512 + base);
        }
#pragma unroll
        for (int i = 0; i < 4; i++) sN[i] = perm_src[min(r0 + 4 + i, r1 - 1)];

        int k = r0;
        for (; k + 3 < r1; k += 4) {
            f16x4 c0 = rr[0], c1 = rr[1], c2 = rr[2], c3 = rr[3];
#pragma unroll
            for (int i = 0; i < 4; i++)
                rr[i] = *(const f16x4*)(xlh + (size_t)sN[i] * 512 + base);
#pragma unroll
            for (int i = 0; i < 4; i++) sN[i] = perm_src[min(k + 8 + i, r1 - 1)];
            edge_upd(c0); edge_upd(c1); edge_upd(c2); edge_upd(c3);
        }
        int rem = r1 - k;
        if (rem > 0) edge_upd(rr[0]);
        if (rem > 1) edge_upd(rr[1]);
        if (rem > 2) edge_upd(rr[2]);
    }

    const float inv = 1.f / l;

    // ---- LayerNorm over 512 ch = this wave (256) + partner wave (256) ----
    __shared__ float red_s[4], red_q[4];
    float bov[4], gmv[4], btv[4];
    *(float4*)(bov) = *(const float4*)(bo + base);
    *(float4*)(gmv) = *(const float4*)(gam + base);
    *(float4*)(btv) = *(const float4*)(bet + base);

    float v[4];
    float s = 0.f;
#pragma unroll
    for (int j = 0; j < 4; j++) {
        v[j] = acc[j] * inv + bov[j];
        s += v[j];
    }
#pragma unroll
    for (int off = 1; off < 64; off <<= 1) s += __shfl_xor(s, off);
    if (lane == 0) red_s[wv] = s;
    __syncthreads();
    const int pbase = wv & 2;
    const float mu = (red_s[pbase] + red_s[pbase | 1]) * (1.f / 512.f);
    float q = 0.f;
#pragma unroll
    for (int j = 0; j < 4; j++) { float dd = v[j] - mu; q += dd * dd; }
#pragma unroll
    for (int off = 1; off < 64; off <<= 1) q += __shfl_xor(q, off);
    if (lane == 0) red_q[wv] = q;
    __syncthreads();
    const float rstd = rsqrtf((red_q[pbase] + red_q[pbase | 1]) * (1.f / 512.f) + LN_EPS);

    f16x4 hv;
#pragma unroll
    for (int j = 0; j < 4; j++) {
        float y = (v[j] - mu) * rstd * gmv[j] + btv[j];
        y = y > 0.f ? y : expm1f(y);
        hv[j] = (_Float16)y;
    }
    *(f16x4*)(ah + (size_t)node * 512 + base) = hv;
}

// ---------- final layer HC=128, H=1: one wave per node, depth-4 pipeline, fp32 out ----------
__global__ __launch_bounds__(256) void gat_ln128(
    const _Float16* __restrict__ xlh, const _Float16* __restrict__ xrh,
    const float* __restrict__ att, const float* __restrict__ bo,
    const float* __restrict__ gam, const float* __restrict__ bet,
    const int* __restrict__ rowptr, const int* __restrict__ perm_src,
    float* __restrict__ xout)
{
    const int lane = threadIdx.x & 63;
    const int wave = threadIdx.x >> 6;
    const int node = blockIdx.x * 4 + wave;
    if (node >= NNODES) return;
    const int base = lane * 2;

    const f16x2 xrp = *(const f16x2*)(xrh + (size_t)node * 128 + base);
    f16x2 w06, w04;
    {
        float2 w0 = *(const float2*)(att + base);
        w06[0] = (_Float16)(0.6f * w0.x); w06[1] = (_Float16)(0.6f * w0.y);
        w04[0] = (_Float16)(0.4f * w0.x); w04[1] = (_Float16)(0.4f * w0.y);
    }

    float l = 0.f;
    float acc[2] = {};

    auto edge_upd = [&](const f16x2 c0) {
        f16x2 v = c0 + xrp;
        f16x2 s = w06 * v + w04 * pk_abs2(v);
        float part = (float)s[0] + (float)s[1];
#pragma unroll
        for (int off = 32; off > 0; off >>= 1) part += __shfl_xor(part, off);
        float pe = __expf(part);
        l += pe;
        acc[0] += pe * (float)c0[0];
        acc[1] += pe * (float)c0[1];
    };

    const int r0 = rowptr[node], r1 = rowptr[node + 1];
    {
        int sN[4];
        f16x2 rr[4];
#pragma unroll
        for (int i = 0; i < 4; i++) {
            int si = perm_src[min(r0 + i, r1 - 1)];
            rr[i] = *(const f16x2*)(xlh + (size_t)si * 128 + base);
        }
#pragma unroll
        for (int i = 0; i < 4; i++) sN[i] = perm_src[min(r0 + 4 + i, r1 - 1)];

        int k = r0;
        for (; k + 3 < r1; k += 4) {
            f16x2 c0 = rr[0], c1 = rr[1], c2 = rr[2], c3 = rr[3];
#pragma unroll
            for (int i = 0; i < 4; i++)
                rr[i] = *(const f16x2*)(xlh + (size_t)sN[i] * 128 + base);
#pragma unroll
            for (int i = 0; i < 4; i++) sN[i] = perm_src[min(k + 8 + i, r1 - 1)];
            edge_upd(c0); edge_upd(c1); edge_upd(c2); edge_upd(c3);
        }
        int rem = r1 - k;
        if (rem > 0) edge_upd(rr[0]);
        if (rem > 1) edge_upd(rr[1]);
        if (rem > 2) edge_upd(rr[2]);
    }

    const float inv = 1.f / l;

    float bov[2], gmv[2], btv[2];
    *(float2*)(bov) = *(const float2*)(bo + base);
    *(float2*)(gmv) = *(const float2*)(gam + base);
    *(float2*)(btv) = *(const float2*)(bet + base);

    float v[2];
    float s = 0.f;
#pragma unroll
    for (int j = 0; j < 2; j++) {
        v[j] = acc[j] * inv + bov[j];
        s += v[j];
    }
#pragma unroll
    for (int off = 1; off < 64; off <<= 1) s += __shfl_xor(s, off);
    const float mu = s * (1.f / 128.f);
    float q = 0.f;
#pragma unroll
    for (int j = 0; j < 2; j++) { float dd = v[j] - mu; q += dd * dd; }
#pragma unroll
    for (int off = 1; off < 64; off <<= 1) q += __shfl_xor(q, off);
    const float rstd = rsqrtf(q * (1.f / 128.f) + LN_EPS);

    float2 o0;
    {
        float y0 = (v[0] - mu) * rstd * gmv[0] + btv[0];
        float y1 = (v[1] - mu) * rstd * gmv[1] + btv[1];
        o0.x = y0 > 0.f ? y0 : expm1f(y0);
        o0.y = y1 > 0.f ? y1 : expm1f(y1);
    }
    *(float2*)(xout + (size_t)node * 128 + base) = o0;
}

// ---------- fused mean-pool (segmented, no atomics) + MLP head ----------
__global__ __launch_bounds__(128) void pool_mlp(
    const float* __restrict__ xfin, const int* __restrict__ batch,
    const float* __restrict__ W1, const float* __restrict__ b1,
    const float* __restrict__ W2, const float* __restrict__ b2,
    const float* __restrict__ W3, const float* __restrict__ b3,
    float* __restrict__ out)
{
    __shared__ int bounds[2];
    __shared__ float pool[128], h1[128], h2[64];
    const int g = blockIdx.x, t = threadIdx.x;
    if (t < 2) {
        int target = g + t;
        int lo = 0, hi = NNODES;
        while (lo < hi) { int mid = (lo + hi) >> 1; if (batch[mid] < target) lo = mid + 1; else hi = mid; }
        bounds[t] = lo;
    }
    __syncthreads();
    const int lo = bounds[0], hi = bounds[1];
    float s = 0.f;
#pragma unroll 4
    for (int n = lo; n < hi; n++) s += xfin[(size_t)n * 128 + t];
    pool[t] = s / (float)max(hi - lo, 1);
    __syncthreads();
    float a = b1[t];
    for (int k = 0; k < 128; k++) a += pool[k] * W1[k * 128 + t];
    h1[t] = fmaxf(a, 0.f);
    __syncthreads();
    if (t < 64) {
        float a2 = b2[t];
        for (int k = 0; k < 128; k++) a2 += h1[k] * W2[k * 64 + t];
        h2[t] = fmaxf(a2, 0.f);
    }
    __syncthreads();
    if (t == 0) {
        float a3 = b3[0];
        for (int k = 0; k < 64; k++) a3 += h2[k] * W3[k];
        out[g] = a3;
    }
}

// =====================================================================
extern "C" void kernel_launch(void* const* d_in, const int* in_sizes, int n_in,
                              void* d_out, int out_size, void* d_ws, size_t ws_size,
                              hipStream_t stream)
{
    const float* x     = (const float*)d_in[0];
    const int*   ei    = (const int*)d_in[1];
    const int*   batch = (const int*)d_in[2];

    const float *Wl[3], *bl[3], *Wr[3], *br[3], *att[3], *bo[3], *ga[3], *be[3];
    for (int l = 0; l < 3; l++) {
        int o = 3 + l * 8;
        Wl[l]  = (const float*)d_in[o + 0];
        bl[l]  = (const float*)d_in[o + 1];
        Wr[l]  = (const float*)d_in[o + 2];
        br[l]  = (const float*)d_in[o + 3];
        att[l] = (const float*)d_in[o + 4];
        bo[l]  = (const float*)d_in[o + 5];
        ga[l]  = (const float*)d_in[o + 6];
        be[l]  = (const float*)d_in[o + 7];
    }
    const float* W1 = (const float*)d_in[27];
    const float* b1 = (const float*)d_in[28];
    const float* W2 = (const float*)d_in[29];
    const float* b2 = (const float*)d_in[30];
    const float* W3 = (const float*)d_in[31];
    const float* b3 = (const float*)d_in[32];

    // workspace layout
    char* w = (char*)d_ws;
    size_t off = 0;
    auto alloc = [&](size_t bytes) {
        void* p = w + off;
        off += (bytes + 255) & ~(size_t)255;
        return p;
    };
    _Float16* xlh  = (_Float16*)alloc((size_t)NNODES * 512 * 2);   // xl (fp16) from GEMM
    _Float16* xrh  = (_Float16*)alloc((size_t)NNODES * 512 * 2);   // xr (fp16) from GEMM
    float*    xfin = (float*)alloc((size_t)NNODES * 128 * 4);      // final layer fp32
    _Float16* Axh  = (_Float16*)alloc((size_t)MPAD * 800 * 2);     // A (reused [MPAD][512] for layers 1/2)
    _Float16* Bh0  = (_Float16*)alloc((size_t)1024 * 800 * 2);
    _Float16* Bh1  = (_Float16*)alloc((size_t)1024 * 512 * 2);
    _Float16* Bh2  = (_Float16*)alloc((size_t)256 * 512 * 2);
    float*    bp0  = (float*)alloc(1024 * 4);
    float*    bp1  = (float*)alloc(1024 * 4);
    float*    bp2  = (float*)alloc(256 * 4);
    int*      deg      = (int*)alloc((size_t)NNODES * 4 * 2);      // deg | cursor (one memset)
    int*      cursor   = deg + NNODES;
    int*      rowptr   = (int*)alloc((size_t)(NNODES + 1) * 4);
    int*      perm_src = (int*)alloc((size_t)ETOT * 4);
    _Float16* Ah1 = Axh;   // [MPAD][512] for layers 1/2

    // ---- input conversion + weight packing ----
    convert_x<<<(MPAD * 800 + 255) / 256, 256, 0, stream>>>(x, Axh);
    pack_w<<<(1024 * 800 + 255) / 256, 256, 0, stream>>>(Wl[0], Wr[0], bl[0], br[0], Bh0, bp0, 771, 800, 512, 1024);
    pack_w<<<(1024 * 512 + 255) / 256, 256, 0, stream>>>(Wl[1], Wr[1], bl[1], br[1], Bh1, bp1, 512, 512, 512, 1024);
    pack_w<<<(256 * 512 + 255) / 256, 256, 0, stream>>>(Wl[2], Wr[2], bl[2], br[2], Bh2, bp2, 512, 512, 128, 256);

    // ---- build CSR by destination ----
    hipMemsetAsync(deg, 0, (size_t)NNODES * 4 * 2, stream);        // deg + cursor
    hist_kernel<<<(ETOT + 255) / 256, 256, 0, stream>>>(ei, deg);
    scan_kernel<<<1, 256, 0, stream>>>(deg, rowptr);
    scatter_kernel<<<(ETOT + 255) / 256, 256, 0, stream>>>(ei, rowptr, cursor, perm_src);

    // ---- layer 0: [10000,771] x [771,1024] ----
    gemm_mfma<<<80 * 8, 256, 0, stream>>>(Axh, Bh0, bp0, xlh, xrh, NNODES, 800, 1024, 3);
    gat_ln512<<<MPAD / 2, 256, 0, stream>>>(
        xlh, xrh, att[0], bo[0], ga[0], be[0], rowptr, perm_src, Ah1);

    // ---- layer 1: [10000,512] x [512,1024] ----
    gemm_mfma<<<80 * 8, 256, 0, stream>>>(Ah1, Bh1, bp1, xlh, xrh, NNODES, 512, 1024, 3);
    gat_ln512<<<MPAD / 2, 256, 0, stream>>>(
        xlh, xrh, att[1], bo[1], ga[1], be[1], rowptr, perm_src, Ah1);

    // ---- layer 2: [10000,512] x [512,256] ----
    gemm_mfma<<<80 * 2, 256, 0, stream>>>(Ah1, Bh2, bp2, xlh, xrh, NNODES, 512, 256, 1);
    gat_ln128<<<(NNODES + 3) / 4, 256, 0, stream>>>(
        xlh, xrh, att[2], bo[2], ga[2], be[2], rowptr, perm_src, xfin);

    // ---- fused pool + MLP ----
    pool_mlp<<<NGRAPH, 128, 0, stream>>>(xfin, batch, W1, b1, W2, b2, W3, b3, (float*)d_out);
}

// Round 11
// 355.752 us; speedup vs baseline: 1.0439x; 1.0439x over previous
//
#include <hip/hip_runtime.h>
#include <math.h>

#define NNODES 10000
#define MPAD   10240               // 80*128, padded row count for MFMA GEMM
#define NEDGES 160000
#define ETOT   (NEDGES + NNODES)   // 170000, with self loops
#define NGRAPH 64
#define LN_EPS 1e-5f
#define NEG_SLOPE 0.2f

typedef _Float16 f16x8 __attribute__((ext_vector_type(8)));
typedef _Float16 f16x2 __attribute__((ext_vector_type(2)));
typedef float    f32x4 __attribute__((ext_vector_type(4)));
typedef unsigned u32x4 __attribute__((ext_vector_type(4)));

__device__ __forceinline__ f16x8 pk_abs8(f16x8 v) {
    u32x4 u; __builtin_memcpy(&u, &v, 16);
    u &= 0x7fff7fffu;
    f16x8 r; __builtin_memcpy(&r, &u, 16);
    return r;
}
__device__ __forceinline__ f16x2 pk_abs2(f16x2 v) {
    unsigned u; __builtin_memcpy(&u, &v, 4);
    u &= 0x7fff7fffu;
    f16x2 r; __builtin_memcpy(&r, &u, 4);
    return r;
}

// ---------- convert x [10000][771] fp32 -> A [MPAD][800] fp16 (zero pad) ----------
__global__ __launch_bounds__(256) void convert_x(
    const float* __restrict__ x, _Float16* __restrict__ ah)
{
    int idx = blockIdx.x * blockDim.x + threadIdx.x;
    if (idx >= MPAD * 800) return;
    int r = idx / 800, k = idx - r * 800;
    float v = (r < NNODES && k < 771) ? x[(size_t)r * 771 + k] : 0.f;
    ah[idx] = (_Float16)v;
}

// ---------- pack weights: Wl|Wr [K][NW] -> B [Np][Kp] fp16 transposed ----------
__global__ __launch_bounds__(256) void pack_w(
    const float* __restrict__ Wl, const float* __restrict__ Wr,
    const float* __restrict__ bl, const float* __restrict__ br,
    _Float16* __restrict__ bh, float* __restrict__ biasp,
    int K, int Kp, int NW, int Np)
{
    int idx = blockIdx.x * blockDim.x + threadIdx.x;
    if (idx < Np) biasp[idx] = (idx < NW) ? bl[idx] : br[idx - NW];
    if (idx >= Np * Kp) return;
    int n = idx / Kp, k = idx - n * Kp;
    float v = 0.f;
    if (k < K) v = (n < NW) ? Wl[(size_t)k * NW + n] : Wr[(size_t)k * NW + (n - NW)];
    bh[idx] = (_Float16)v;
}

// ---------- fp16 MFMA GEMM: C[M][N] = A[M][Kp] @ B[Kp][N] + bias ----------
// 128x128 tile, 4 waves x 64x64, BK=32, 16x16x32 f16 MFMA, XCD-aware 1-D grid,
// 2-way-aliasing LDS swizzle. Epilogue: cols<N/2 -> xl fp16; cols>=N/2 -> xr fp16.
__global__ __launch_bounds__(256) void gemm_mfma(
    const _Float16* __restrict__ Ah, const _Float16* __restrict__ Bh,
    const float* __restrict__ bias,
    _Float16* __restrict__ xlh, _Float16* __restrict__ xrh,
    int M, int Kp, int N, int lognbx)
{
    __shared__ __align__(16) _Float16 sAh[128 * 32];
    __shared__ __align__(16) _Float16 sBh[128 * 32];

    const int tid  = threadIdx.x;
    const int lane = tid & 63;
    const int wave = tid >> 6;
    const int L    = blockIdx.x;
    const int xcd  = L & 7;
    const int t    = L >> 3;
    const int bx   = t & ((1 << lognbx) - 1);
    const int by   = xcd + 8 * (t >> lognbx);
    const int row0 = by * 128;
    const int col0 = bx * 128;
    const int wr = (wave >> 1) * 64;
    const int wc = (wave & 1) * 64;
    const int fm = lane & 15;
    const int fq = lane >> 4;

    f32x4 acc[4][4] = {};

    for (int k0 = 0; k0 < Kp; k0 += 32) {
#pragma unroll
        for (int it = 0; it < 2; ++it) {
            int c  = tid + it * 256;             // 0..511 16B chunks per tile
            int r  = c >> 2;
            int kc = (c & 3) ^ ((r >> 1) & 3);   // swizzled global k-chunk
            size_t ga = (size_t)(row0 + r) * Kp + k0 + kc * 8;
            size_t gb = (size_t)(col0 + r) * Kp + k0 + kc * 8;
            __builtin_amdgcn_global_load_lds(
                (const __attribute__((address_space(1))) void*)(Ah + ga),
                (__attribute__((address_space(3))) void*)(sAh + c * 8), 16, 0, 0);
            __builtin_amdgcn_global_load_lds(
                (const __attribute__((address_space(1))) void*)(Bh + gb),
                (__attribute__((address_space(3))) void*)(sBh + c * 8), 16, 0, 0);
        }
        __syncthreads();

        f16x8 fah[4], fbh[4];
#pragma unroll
        for (int mi = 0; mi < 4; ++mi) {
            int m = wr + mi * 16 + fm;
            int off = (m * 4 + (fq ^ ((m >> 1) & 3))) * 8;
            fah[mi] = *(const f16x8*)(sAh + off);
        }
#pragma unroll
        for (int ni = 0; ni < 4; ++ni) {
            int n = wc + ni * 16 + fm;
            int off = (n * 4 + (fq ^ ((n >> 1) & 3))) * 8;
            fbh[ni] = *(const f16x8*)(sBh + off);
        }
#pragma unroll
        for (int mi = 0; mi < 4; ++mi)
#pragma unroll
            for (int ni = 0; ni < 4; ++ni)
                acc[mi][ni] = __builtin_amdgcn_mfma_f32_16x16x32_f16(fah[mi], fbh[ni], acc[mi][ni], 0, 0, 0);
        __syncthreads();
    }

    const int NH = N >> 1;
    float bv[4];
#pragma unroll
    for (int ni = 0; ni < 4; ++ni) bv[ni] = bias[col0 + wc + ni * 16 + fm];
#pragma unroll
    for (int mi = 0; mi < 4; ++mi) {
        int grb = row0 + wr + mi * 16 + fq * 4;
#pragma unroll
        for (int reg = 0; reg < 4; ++reg) {
            int gr = grb + reg;
            if (gr < M) {
#pragma unroll
                for (int ni = 0; ni < 4; ++ni) {
                    int gc = col0 + wc + ni * 16 + fm;
                    float val = acc[mi][ni][reg] + bv[ni];
                    if (gc < NH) xlh[(size_t)gr * NH + gc] = (_Float16)val;
                    else         xrh[(size_t)gr * NH + gc - NH] = (_Float16)val;
                }
            }
        }
    }
}

// ---------- CSR build ----------
__global__ __launch_bounds__(256) void hist_kernel(
    const int* __restrict__ ei, int* __restrict__ deg)
{
    int e = blockIdx.x * blockDim.x + threadIdx.x;
    if (e >= ETOT) return;
    int d = (e < NEDGES) ? ei[NEDGES + e] : e - NEDGES;
    atomicAdd(&deg[d], 1);
}

__global__ __launch_bounds__(256) void scan_kernel(
    const int* __restrict__ deg, int* __restrict__ rowptr)
{
    __shared__ int partial[256];
    const int t = threadIdx.x;
    const int CH = (NNODES + 255) / 256;
    const int lo = t * CH, hi = min(lo + CH, NNODES);
    int s = 0;
    for (int i = lo; i < hi; i++) s += deg[i];
    partial[t] = s;
    __syncthreads();
    for (int off = 1; off < 256; off <<= 1) {
        int v = (t >= off) ? partial[t - off] : 0;
        __syncthreads();
        partial[t] += v;
        __syncthreads();
    }
    int run = partial[t] - s;
    for (int i = lo; i < hi; i++) { rowptr[i] = run; run += deg[i]; }
    if (t == 255) rowptr[NNODES] = partial[255];
}

__global__ __launch_bounds__(256) void scatter_kernel(
    const int* __restrict__ ei, const int* __restrict__ rowptr,
    int* __restrict__ cursor, int* __restrict__ perm_src)
{
    int e = blockIdx.x * blockDim.x + threadIdx.x;
    if (e >= ETOT) return;
    int s, d;
    if (e < NEDGES) { s = ei[e]; d = ei[NEDGES + e]; }
    else { s = e - NEDGES; d = s; }
    int pos = atomicAdd(&cursor[d], 1);
    perm_src[rowptr[d] + pos] = s;
}

// ---------- fused GATv2 edge phase + bias + LayerNorm + ELU ----------
// One wave per dst node. Packed-fp16 logit math:
//   leaky(v) = 0.6v + 0.4|v|  =>  logit = sum (0.6 att)*v + (0.4 att)*|v|
// No max-subtraction (logits provably small, exp safe in fp32).
// Edge loop: depth-4 rotation pipeline (4 full-width loads outstanding),
// clamped branch-free prefetch. Invariant: rr = rows of edges k..k+3,
// sN = indices of edges k+4..k+7.
template<int HC, int H, bool EMIT>
__global__ __launch_bounds__(256) void gat_ln(
    const _Float16* __restrict__ xlh, const _Float16* __restrict__ xrh,
    const float* __restrict__ att, const float* __restrict__ bo,
    const float* __restrict__ gam, const float* __restrict__ bet,
    const int* __restrict__ rowptr, const int* __restrict__ perm_src,
    float* __restrict__ xout, _Float16* __restrict__ ah)
{
    constexpr int C = HC / H;
    constexpr int P = HC / 64;
    constexpr int GRP = C / P;
    const int lane = threadIdx.x & 63;
    const int wave = threadIdx.x >> 6;
    const int node = blockIdx.x * 4 + wave;
    const int base = lane * P;

    if (EMIT && node >= NNODES) {       // zero GEMM pad rows
        if (node < MPAD) {
            f16x8 z = {};
            *(f16x8*)(ah + (size_t)node * HC + base) = z;
        }
        return;
    }
    if (node >= NNODES) return;

    float l = 0.f;
    float acc[P];
#pragma unroll
    for (int j = 0; j < P; j++) acc[j] = 0.f;

    const int r0 = rowptr[node], r1 = rowptr[node + 1];

    if constexpr (P == 8) {
        const f16x8 xrp = *(const f16x8*)(xrh + (size_t)node * HC + base);
        f16x8 w06, w04;
        {
            float4 w0 = *(const float4*)(att + base);
            float4 w1 = *(const float4*)(att + base + 4);
            float wa[8] = { w0.x, w0.y, w0.z, w0.w, w1.x, w1.y, w1.z, w1.w };
#pragma unroll
            for (int j = 0; j < 8; j++) {
                w06[j] = (_Float16)(0.6f * wa[j]);
                w04[j] = (_Float16)(0.4f * wa[j]);
            }
        }
        auto edge_upd = [&](const f16x8 c0) {
            f16x8 v = c0 + xrp;                       // pk_add
            f16x8 s = w06 * v + w04 * pk_abs8(v);     // pk_mul/pk_fma + and
            f16x2 h = (__builtin_shufflevector(s, s, 0, 1) + __builtin_shufflevector(s, s, 2, 3))
                    + (__builtin_shufflevector(s, s, 4, 5) + __builtin_shufflevector(s, s, 6, 7));
            float part = (float)h[0] + (float)h[1];
#pragma unroll
            for (int off = GRP / 2; off > 0; off >>= 1) part += __shfl_xor(part, off);
            float pe = __expf(part);
            l += pe;
#pragma unroll
            for (int j = 0; j < 8; j++) acc[j] += pe * (float)c0[j];
        };

        int sN[4];
        f16x8 rr[4];
#pragma unroll
        for (int i = 0; i < 4; i++) sN[i] = perm_src[min(r0 + i, r1 - 1)];
#pragma unroll
        for (int i = 0; i < 4; i++) rr[i] = *(const f16x8*)(xlh + (size_t)sN[i] * HC + base);
#pragma unroll
        for (int i = 0; i < 4; i++) sN[i] = perm_src[min(r0 + 4 + i, r1 - 1)];

        int k = r0;
        for (; k + 3 < r1; k += 4) {
            f16x8 c0 = rr[0], c1 = rr[1], c2 = rr[2], c3 = rr[3];
#pragma unroll
            for (int i = 0; i < 4; i++) rr[i] = *(const f16x8*)(xlh + (size_t)sN[i] * HC + base);
#pragma unroll
            for (int i = 0; i < 4; i++) sN[i] = perm_src[min(k + 8 + i, r1 - 1)];
            edge_upd(c0); edge_upd(c1); edge_upd(c2); edge_upd(c3);
        }
        int rem = r1 - k;
        if (rem > 0) edge_upd(rr[0]);
        if (rem > 1) edge_upd(rr[1]);
        if (rem > 2) edge_upd(rr[2]);
    } else {
        const f16x2 xrp = *(const f16x2*)(xrh + (size_t)node * HC + base);
        f16x2 w06, w04;
        {
            float2 w0 = *(const float2*)(att + base);
            w06[0] = (_Float16)(0.6f * w0.x); w06[1] = (_Float16)(0.6f * w0.y);
            w04[0] = (_Float16)(0.4f * w0.x); w04[1] = (_Float16)(0.4f * w0.y);
        }
        auto edge_upd = [&](const f16x2 c0) {
            f16x2 v = c0 + xrp;
            f16x2 s = w06 * v + w04 * pk_abs2(v);
            float part = (float)s[0] + (float)s[1];
#pragma unroll
            for (int off = GRP / 2; off > 0; off >>= 1) part += __shfl_xor(part, off);
            float pe = __expf(part);
            l += pe;
            acc[0] += pe * (float)c0[0];
            acc[1] += pe * (float)c0[1];
        };

        int sN[4];
        f16x2 rr[4];
#pragma unroll
        for (int i = 0; i < 4; i++) sN[i] = perm_src[min(r0 + i, r1 - 1)];
#pragma unroll
        for (int i = 0; i < 4; i++) rr[i] = *(const f16x2*)(xlh + (size_t)sN[i] * HC + base);
#pragma unroll
        for (int i = 0; i < 4; i++) sN[i] = perm_src[min(r0 + 4 + i, r1 - 1)];

        int k = r0;
        for (; k + 3 < r1; k += 4) {
            f16x2 c0 = rr[0], c1 = rr[1], c2 = rr[2], c3 = rr[3];
#pragma unroll
            for (int i = 0; i < 4; i++) rr[i] = *(const f16x2*)(xlh + (size_t)sN[i] * HC + base);
#pragma unroll
            for (int i = 0; i < 4; i++) sN[i] = perm_src[min(k + 8 + i, r1 - 1)];
            edge_upd(c0); edge_upd(c1); edge_upd(c2); edge_upd(c3);
        }
        int rem = r1 - k;
        if (rem > 0) edge_upd(rr[0]);
        if (rem > 1) edge_upd(rr[1]);
        if (rem > 2) edge_upd(rr[2]);
    }

    const float inv = 1.f / l;

    // ---- LayerNorm across the wave (all HC channels of this node) ----
    float bov[P], gmv[P], btv[P];
    if constexpr (P == 8) {
        *(float4*)(bov)     = *(const float4*)(bo + base);
        *(float4*)(bov + 4) = *(const float4*)(bo + base + 4);
        *(float4*)(gmv)     = *(const float4*)(gam + base);
        *(float4*)(gmv + 4) = *(const float4*)(gam + base + 4);
        *(float4*)(btv)     = *(const float4*)(bet + base);
        *(float4*)(btv + 4) = *(const float4*)(bet + base + 4);
    } else {
        *(float2*)(bov) = *(const float2*)(bo + base);
        *(float2*)(gmv) = *(const float2*)(gam + base);
        *(float2*)(btv) = *(const float2*)(bet + base);
    }

    float v[P];
    float s = 0.f;
#pragma unroll
    for (int j = 0; j < P; j++) {
        v[j] = acc[j] * inv + bov[j];
        s += v[j];
    }
#pragma unroll
    for (int off = 1; off < 64; off <<= 1) s += __shfl_xor(s, off);
    const float mu = s / (float)HC;
    float q = 0.f;
#pragma unroll
    for (int j = 0; j < P; j++) { float dd = v[j] - mu; q += dd * dd; }
#pragma unroll
    for (int off = 1; off < 64; off <<= 1) q += __shfl_xor(q, off);
    const float rstd = rsqrtf(q / (float)HC + LN_EPS);

    if constexpr (EMIT) {
        f16x8 hv;
#pragma unroll
        for (int j = 0; j < P; j++) {
            float y = (v[j] - mu) * rstd * gmv[j] + btv[j];
            y = y > 0.f ? y : expm1f(y);
            hv[j] = (_Float16)y;
        }
        *(f16x8*)(ah + (size_t)node * HC + base) = hv;
    } else {
        float o[P];
#pragma unroll
        for (int j = 0; j < P; j++) {
            float y = (v[j] - mu) * rstd * gmv[j] + btv[j];
            o[j] = y > 0.f ? y : expm1f(y);
        }
        if constexpr (P == 2) {
            float2 o0 = { o[0], o[1] };
            *(float2*)(xout + (size_t)node * HC + base) = o0;
        } else {
            float4 o0 = { o[0], o[1], o[2], o[3] };
            float4 o1 = { o[4], o[5], o[6], o[7] };
            *(float4*)(xout + (size_t)node * HC + base) = o0;
            *(float4*)(xout + (size_t)node * HC + base + 4) = o1;
        }
    }
}

// ---------- fused mean-pool (segmented, no atomics) + MLP head ----------
__global__ __launch_bounds__(128) void pool_mlp(
    const float* __restrict__ xfin, const int* __restrict__ batch,
    const float* __restrict__ W1, const float* __restrict__ b1,
    const float* __restrict__ W2, const float* __restrict__ b2,
    const float* __restrict__ W3, const float* __restrict__ b3,
    float* __restrict__ out)
{
    __shared__ int bounds[2];
    __shared__ float pool[128], h1[128], h2[64];
    const int g = blockIdx.x, t = threadIdx.x;
    if (t < 2) {
        int target = g + t;
        int lo = 0, hi = NNODES;
        while (lo < hi) { int mid = (lo + hi) >> 1; if (batch[mid] < target) lo = mid + 1; else hi = mid; }
        bounds[t] = lo;
    }
    __syncthreads();
    const int lo = bounds[0], hi = bounds[1];
    float s = 0.f;
#pragma unroll 4
    for (int n = lo; n < hi; n++) s += xfin[(size_t)n * 128 + t];
    pool[t] = s / (float)max(hi - lo, 1);
    __syncthreads();
    float a = b1[t];
    for (int k = 0; k < 128; k++) a += pool[k] * W1[k * 128 + t];
    h1[t] = fmaxf(a, 0.f);
    __syncthreads();
    if (t < 64) {
        float a2 = b2[t];
        for (int k = 0; k < 128; k++) a2 += h1[k] * W2[k * 64 + t];
        h2[t] = fmaxf(a2, 0.f);
    }
    __syncthreads();
    if (t == 0) {
        float a3 = b3[0];
        for (int k = 0; k < 64; k++) a3 += h2[k] * W3[k];
        out[g] = a3;
    }
}

// =====================================================================
extern "C" void kernel_launch(void* const* d_in, const int* in_sizes, int n_in,
                              void* d_out, int out_size, void* d_ws, size_t ws_size,
                              hipStream_t stream)
{
    const float* x     = (const float*)d_in[0];
    const int*   ei    = (const int*)d_in[1];
    const int*   batch = (const int*)d_in[2];

    const float *Wl[3], *bl[3], *Wr[3], *br[3], *att[3], *bo[3], *ga[3], *be[3];
    for (int l = 0; l < 3; l++) {
        int o = 3 + l * 8;
        Wl[l]  = (const float*)d_in[o + 0];
        bl[l]  = (const float*)d_in[o + 1];
        Wr[l]  = (const float*)d_in[o + 2];
        br[l]  = (const float*)d_in[o + 3];
        att[l] = (const float*)d_in[o + 4];
        bo[l]  = (const float*)d_in[o + 5];
        ga[l]  = (const float*)d_in[o + 6];
        be[l]  = (const float*)d_in[o + 7];
    }
    const float* W1 = (const float*)d_in[27];
    const float* b1 = (const float*)d_in[28];
    const float* W2 = (const float*)d_in[29];
    const float* b2 = (const float*)d_in[30];
    const float* W3 = (const float*)d_in[31];
    const float* b3 = (const float*)d_in[32];

    // workspace layout
    char* w = (char*)d_ws;
    size_t off = 0;
    auto alloc = [&](size_t bytes) {
        void* p = w + off;
        off += (bytes + 255) & ~(size_t)255;
        return p;
    };
    _Float16* xlh  = (_Float16*)alloc((size_t)NNODES * 512 * 2);   // xl (fp16) from GEMM
    _Float16* xrh  = (_Float16*)alloc((size_t)NNODES * 512 * 2);   // xr (fp16) from GEMM
    float*    xfin = (float*)alloc((size_t)NNODES * 128 * 4);      // final layer fp32
    _Float16* Axh  = (_Float16*)alloc((size_t)MPAD * 800 * 2);     // A (reused [MPAD][512] for layers 1/2)
    _Float16* Bh0  = (_Float16*)alloc((size_t)1024 * 800 * 2);
    _Float16* Bh1  = (_Float16*)alloc((size_t)1024 * 512 * 2);
    _Float16* Bh2  = (_Float16*)alloc((size_t)256 * 512 * 2);
    float*    bp0  = (float*)alloc(1024 * 4);
    float*    bp1  = (float*)alloc(1024 * 4);
    float*    bp2  = (float*)alloc(256 * 4);
    int*      deg      = (int*)alloc((size_t)NNODES * 4 * 2);      // deg | cursor (one memset)
    int*      cursor   = deg + NNODES;
    int*      rowptr   = (int*)alloc((size_t)(NNODES + 1) * 4);
    int*      perm_src = (int*)alloc((size_t)ETOT * 4);
    _Float16* Ah1 = Axh;   // [MPAD][512] for layers 1/2

    // ---- input conversion + weight packing ----
    convert_x<<<(MPAD * 800 + 255) / 256, 256, 0, stream>>>(x, Axh);
    pack_w<<<(1024 * 800 + 255) / 256, 256, 0, stream>>>(Wl[0], Wr[0], bl[0], br[0], Bh0, bp0, 771, 800, 512, 1024);
    pack_w<<<(1024 * 512 + 255) / 256, 256, 0, stream>>>(Wl[1], Wr[1], bl[1], br[1], Bh1, bp1, 512, 512, 512, 1024);
    pack_w<<<(256 * 512 + 255) / 256, 256, 0, stream>>>(Wl[2], Wr[2], bl[2], br[2], Bh2, bp2, 512, 512, 128, 256);

    // ---- build CSR by destination ----
    hipMemsetAsync(deg, 0, (size_t)NNODES * 4 * 2, stream);        // deg + cursor
    hist_kernel<<<(ETOT + 255) / 256, 256, 0, stream>>>(ei, deg);
    scan_kernel<<<1, 256, 0, stream>>>(deg, rowptr);
    scatter_kernel<<<(ETOT + 255) / 256, 256, 0, stream>>>(ei, rowptr, cursor, perm_src);

    const int fgrid_pad = (MPAD + 3) / 4;     // covers pad rows for fp16 emit
    const int fgrid     = (NNODES + 3) / 4;

    // ---- layer 0: [10000,771] x [771,1024] ----
    gemm_mfma<<<80 * 8, 256, 0, stream>>>(Axh, Bh0, bp0, xlh, xrh, NNODES, 800, 1024, 3);
    gat_ln<512, 4, true><<<fgrid_pad, 256, 0, stream>>>(
        xlh, xrh, att[0], bo[0], ga[0], be[0], rowptr, perm_src, nullptr, Ah1);

    // ---- layer 1: [10000,512] x [512,1024] ----
    gemm_mfma<<<80 * 8, 256, 0, stream>>>(Ah1, Bh1, bp1, xlh, xrh, NNODES, 512, 1024, 3);
    gat_ln<512, 4, true><<<fgrid_pad, 256, 0, stream>>>(
        xlh, xrh, att[1], bo[1], ga[1], be[1], rowptr, perm_src, nullptr, Ah1);

    // ---- layer 2: [10000,512] x [512,256] ----
    gemm_mfma<<<80 * 2, 256, 0, stream>>>(Ah1, Bh2, bp2, xlh, xrh, NNODES, 512, 256, 1);
    gat_ln<128, 1, false><<<fgrid, 256, 0, stream>>>(
        xlh, xrh, att[2], bo[2], ga[2], be[2], rowptr, perm_src, xfin, nullptr);

    // ---- fused pool + MLP ----
    pool_mlp<<<NGRAPH, 128, 0, stream>>>(xfin, batch, W1, b1, W2, b2, W3, b3, (float*)d_out);
}